// Round 1
// baseline (305.579 us; speedup 1.0000x reference)
//
#include <hip/hip_runtime.h>
#include <stdint.h>

#define NB   128    // batch
#define CC   224    // channels
#define HW   32     // H = W
#define NWIN 16     // windows
#define NPOS 64     // positions per block (16 windows x 4 cols)
#define DH   28     // head dim
#define NHEADS 8

using bf16x8 = __attribute__((ext_vector_type(8))) short;
using u16x4  = __attribute__((ext_vector_type(4))) unsigned short;
using f32x4  = __attribute__((ext_vector_type(4))) float;

__device__ inline unsigned short f2bf(float f) {
    union { float f; unsigned u; } v; v.f = f;
    unsigned u = v.u;
    u += 0x7fffu + ((u >> 16) & 1u);
    return (unsigned short)(u >> 16);
}

// ---- prep: transpose weights to bf16 [sel][n][k], sel = Q,K,V,O ----
__global__ void prep_weights(const float* __restrict__ Wq, const float* __restrict__ Wk,
                             const float* __restrict__ Wv, const float* __restrict__ Wo,
                             unsigned short* __restrict__ wt) {
    int e = blockIdx.x * blockDim.x + threadIdx.x;
    if (e >= 4 * CC * CC) return;
    int sel = e / (CC * CC);
    int rem = e % (CC * CC);
    int n = rem / CC, k = rem % CC;
    const float* W = (sel == 0) ? Wq : (sel == 1) ? Wk : (sel == 2) ? Wv : Wo;
    wt[e] = f2bf(W[k * CC + n]);
}

// ---- shared memory layout (bytes) ----
#define XS_OFF   0        // ushort [64][232]  x staging (later: o_block bf16)
#define QS_OFF   29696    // ushort [64][232]  q (scaled)
#define KS_OFF   59392    // ushort [64][232]  k
#define VT_OFF   89088    // ushort [224][72]  v transposed: [ch][mcl*16 + widx]
#define POS_OFF  121344   // float  [8][16][16]
#define ATT_OFF  129536   // ushort [8 waves][16][20]
#define SMEM_BYTES 134656
// oout: float [64][225] overlaid on QS+KS (29696 .. 87296 < 89088)

__global__ void __launch_bounds__(512, 1) attn_fused(
    const float* __restrict__ x, const unsigned short* __restrict__ wt,
    const float* __restrict__ bo, const float* __restrict__ pos,
    const float* __restrict__ scale, float* __restrict__ out)
{
    extern __shared__ char smem[];
    unsigned short* xs   = (unsigned short*)(smem + XS_OFF);
    unsigned short* qs   = (unsigned short*)(smem + QS_OFF);
    unsigned short* ks   = (unsigned short*)(smem + KS_OFF);
    unsigned short* vt   = (unsigned short*)(smem + VT_OFF);
    float*          poss = (float*)         (smem + POS_OFF);
    unsigned short* att  = (unsigned short*)(smem + ATT_OFF);
    unsigned short* ob   = xs;                       // phase2 out / phase3 in
    float*          oout = (float*)(smem + QS_OFF);  // phase3 out (f32 [64][225])

    const int tid = threadIdx.x;
    const int wv  = tid >> 6;        // wave 0..7
    const int l   = tid & 63;
    const int g   = l >> 4;          // 0..3
    const int li  = l & 15;
    const int bid = blockIdx.x;
    const int bi  = bid >> 4;
    const int mr  = (bid >> 1) & 7;
    const int hf  = bid & 1;

    // ---- prologue: stage x -> LDS bf16 [p][ch], stage pos_emb ----
    {
        const float* xb = x + ((size_t)bi * CC << 10);
        for (int q = tid; q < CC * NWIN; q += 512) {
            int ch = q >> 4, wx = q & 15;
            int wi = wx >> 2, wj = wx & 3;
            int h = wi * 8 + mr, w0 = wj * 8 + hf * 4;
            float4 v4 = *(const float4*)(xb + (ch << 10) + (h << 5) + w0);
            int p = wx * 4;
            unsigned short* dst = xs + ch;
            dst[(p + 0) * 232] = f2bf(v4.x);
            dst[(p + 1) * 232] = f2bf(v4.y);
            dst[(p + 2) * 232] = f2bf(v4.z);
            dst[(p + 3) * 232] = f2bf(v4.w);
        }
        for (int e = tid; e < NHEADS * NWIN * NWIN; e += 512) poss[e] = pos[e];
    }
    const float scl = scale[0];
    __syncthreads();

    // ---- phase 1: Q,K,V = xs @ Wt   (84 supertiles: 2 M-tiles x 42 N-tiles) ----
    for (int st = wv; st < 84; st += 8) {
        int mt2 = st / 42, ntg = st % 42;
        int sel = ntg / 14, ntl = ntg % 14;
        const unsigned short* wsel = wt + sel * (CC * CC) + (ntl * 16 + li) * CC;
        f32x4 acc0 = {0.f, 0.f, 0.f, 0.f}, acc1 = {0.f, 0.f, 0.f, 0.f};
        int r0 = (mt2 * 2) * 16 + li, r1 = r0 + 16;
        for (int kk = 0; kk < 7; ++kk) {
            int ko = kk * 32 + g * 8;
            bf16x8 bf = *(const bf16x8*)(wsel + ko);
            bf16x8 a0 = *(const bf16x8*)(xs + r0 * 232 + ko);
            bf16x8 a1 = *(const bf16x8*)(xs + r1 * 232 + ko);
            acc0 = __builtin_amdgcn_mfma_f32_16x16x32_bf16(a0, bf, acc0, 0, 0, 0);
            acc1 = __builtin_amdgcn_mfma_f32_16x16x32_bf16(a1, bf, acc1, 0, 0, 0);
        }
        int colb = ntl * 16 + li;
        for (int r = 0; r < 4; ++r) {
            int row0 = (mt2 * 2) * 16 + g * 4 + r, row1 = row0 + 16;
            float v0 = acc0[r], v1 = acc1[r];
            if (sel == 0) {
                qs[row0 * 232 + colb] = f2bf(v0 * scl);
                qs[row1 * 232 + colb] = f2bf(v1 * scl);
            } else if (sel == 1) {
                ks[row0 * 232 + colb] = f2bf(v0);
                ks[row1 * 232 + colb] = f2bf(v1);
            } else {
                vt[colb * 72 + (row0 & 3) * 16 + (row0 >> 2)] = f2bf(v0);
                vt[colb * 72 + (row1 & 3) * 16 + (row1 >> 2)] = f2bf(v1);
            }
        }
    }
    __syncthreads();

    // ---- phase 2: attention. wave wv = head, loops over 4 mcl ----
    {
        const int hd = wv;
        const int cb = hd * DH;
        unsigned short* attw = att + wv * (16 * 20);
        for (int mcl = 0; mcl < 4; ++mcl) {
            int rowq = li * 4 + mcl;
            bf16x8 aq, bk;
            {
                const unsigned short* qp = qs + rowq * 232 + cb + g * 8;
                const unsigned short* kp = ks + rowq * 232 + cb + g * 8;
                u16x4 qlo = *(const u16x4*)qp, qhi = *(const u16x4*)(qp + 4);
                u16x4 klo = *(const u16x4*)kp, khi = *(const u16x4*)(kp + 4);
                if (g == 3) { qhi = (u16x4)0; khi = (u16x4)0; }  // k >= 28: zero both operands
                for (int j = 0; j < 4; ++j) {
                    aq[j] = (short)qlo[j]; aq[4 + j] = (short)qhi[j];
                    bk[j] = (short)klo[j]; bk[4 + j] = (short)khi[j];
                }
            }
            f32x4 sim = {0.f, 0.f, 0.f, 0.f};
            sim = __builtin_amdgcn_mfma_f32_16x16x32_bf16(aq, bk, sim, 0, 0, 0);
            // softmax: row i = g*4+r across 16 lanes (col j = li)
            for (int r = 0; r < 4; ++r) {
                int i = g * 4 + r;
                float s = sim[r] + poss[(hd * 16 + i) * 16 + li];
                float mx = s;
                mx = fmaxf(mx, __shfl_xor(mx, 1, 16));
                mx = fmaxf(mx, __shfl_xor(mx, 2, 16));
                mx = fmaxf(mx, __shfl_xor(mx, 4, 16));
                mx = fmaxf(mx, __shfl_xor(mx, 8, 16));
                float e = __expf(s - mx);
                float sm = e;
                sm += __shfl_xor(sm, 1, 16);
                sm += __shfl_xor(sm, 2, 16);
                sm += __shfl_xor(sm, 4, 16);
                sm += __shfl_xor(sm, 8, 16);
                attw[i * 20 + li] = f2bf(e / sm);
            }
            // PV: o[i][dh] = sum_j attn[i][j] * v2[j][dh]
            bf16x8 pa;
            if (g < 2) {
                const unsigned short* ap = attw + li * 20 + g * 8;
                u16x4 alo = *(const u16x4*)ap, ahi = *(const u16x4*)(ap + 4);
                for (int j = 0; j < 4; ++j) { pa[j] = (short)alo[j]; pa[4 + j] = (short)ahi[j]; }
            } else {
                pa = (bf16x8)0;
            }
            for (int dt = 0; dt < 2; ++dt) {
                bf16x8 bv;
                if (g < 2) {
                    bv = *(const bf16x8*)(vt + (cb + dt * 16 + li) * 72 + mcl * 16 + g * 8);
                } else {
                    bv = (bf16x8)0;
                }
                f32x4 po = {0.f, 0.f, 0.f, 0.f};
                po = __builtin_amdgcn_mfma_f32_16x16x32_bf16(pa, bv, po, 0, 0, 0);
                int dh = dt * 16 + li;
                if (dh < DH) {
                    for (int r = 0; r < 4; ++r) {
                        int i = g * 4 + r;
                        ob[(i * 4 + mcl) * 232 + cb + dh] = f2bf(po[r]);
                    }
                }
            }
        }
    }
    __syncthreads();

    // ---- phase 3: out = ob @ WoT  (28 supertiles: 2 M-tiles x 14 N-tiles) ----
    for (int st = wv; st < 28; st += 8) {
        int mt2 = st / 14, ntl = st % 14;
        const unsigned short* wsel = wt + 3 * (CC * CC) + (ntl * 16 + li) * CC;
        f32x4 acc0 = {0.f, 0.f, 0.f, 0.f}, acc1 = {0.f, 0.f, 0.f, 0.f};
        int r0 = (mt2 * 2) * 16 + li, r1 = r0 + 16;
        for (int kk = 0; kk < 7; ++kk) {
            int ko = kk * 32 + g * 8;
            bf16x8 bf = *(const bf16x8*)(wsel + ko);
            bf16x8 a0 = *(const bf16x8*)(ob + r0 * 232 + ko);
            bf16x8 a1 = *(const bf16x8*)(ob + r1 * 232 + ko);
            acc0 = __builtin_amdgcn_mfma_f32_16x16x32_bf16(a0, bf, acc0, 0, 0, 0);
            acc1 = __builtin_amdgcn_mfma_f32_16x16x32_bf16(a1, bf, acc1, 0, 0, 0);
        }
        int colb = ntl * 16 + li;
        for (int r = 0; r < 4; ++r) {
            int row0 = (mt2 * 2) * 16 + g * 4 + r;
            oout[row0 * 225 + colb] = acc0[r];
            oout[(row0 + 16) * 225 + colb] = acc1[r];
        }
    }
    __syncthreads();

    // ---- final: out[b][ch][h][w] = oout[p][ch] + bo[ch], float4 stores ----
    {
        float* outb = out + ((size_t)bi * CC << 10);
        for (int q = tid; q < CC * NWIN; q += 512) {
            int ch = q >> 4, wx = q & 15;
            int wi = wx >> 2, wj = wx & 3;
            int h = wi * 8 + mr, w0 = wj * 8 + hf * 4;
            int p = wx * 4;
            float b = bo[ch];
            float4 v4;
            v4.x = oout[(p + 0) * 225 + ch] + b;
            v4.y = oout[(p + 1) * 225 + ch] + b;
            v4.z = oout[(p + 2) * 225 + ch] + b;
            v4.w = oout[(p + 3) * 225 + ch] + b;
            *(float4*)(outb + (ch << 10) + (h << 5) + w0) = v4;
        }
    }
}

extern "C" void kernel_launch(void* const* d_in, const int* in_sizes, int n_in,
                              void* d_out, int out_size, void* d_ws, size_t ws_size,
                              hipStream_t stream) {
    const float* x   = (const float*)d_in[0];
    const float* Wq  = (const float*)d_in[1];
    const float* Wk  = (const float*)d_in[2];
    const float* Wv  = (const float*)d_in[3];
    const float* Wo  = (const float*)d_in[4];
    const float* bo  = (const float*)d_in[5];
    const float* pos = (const float*)d_in[6];
    const float* scl = (const float*)d_in[7];
    float* out = (float*)d_out;
    unsigned short* wt = (unsigned short*)d_ws;   // 4*224*224*2 = 401408 B

    prep_weights<<<dim3((4 * CC * CC + 255) / 256), dim3(256), 0, stream>>>(Wq, Wk, Wv, Wo, wt);

    (void)hipFuncSetAttribute((const void*)attn_fused,
                              hipFuncAttributeMaxDynamicSharedMemorySize, SMEM_BYTES);
    attn_fused<<<dim3(NB * 8 * 2), dim3(512), SMEM_BYTES, stream>>>(x, wt, bo, pos, scl, out);
}

// Round 3
// 270.187 us; speedup vs baseline: 1.1310x; 1.1310x over previous
//
#include <hip/hip_runtime.h>
#include <stdint.h>

#define NB   128    // batch
#define CC   224    // channels
#define NWIN 16     // windows
#define DH   28     // head dim
#define NHEADS 8

using bf16x8 = __attribute__((ext_vector_type(8))) short;
using u16x4  = __attribute__((ext_vector_type(4))) unsigned short;
using f32x4  = __attribute__((ext_vector_type(4))) float;

__device__ inline unsigned short f2bf(float f) {
    union { float f; unsigned u; } v; v.f = f;
    unsigned u = v.u;
    u += 0x7fffu + ((u >> 16) & 1u);
    return (unsigned short)(u >> 16);
}

// ---- prep: transpose weights to bf16 [sel][n][k], sel = Q,K,V,O ----
__global__ void prep_weights(const float* __restrict__ Wq, const float* __restrict__ Wk,
                             const float* __restrict__ Wv, const float* __restrict__ Wo,
                             unsigned short* __restrict__ wt) {
    int e = blockIdx.x * blockDim.x + threadIdx.x;
    if (e >= 4 * CC * CC) return;
    int sel = e / (CC * CC);
    int rem = e % (CC * CC);
    int n = rem / CC, k = rem % CC;
    const float* W = (sel == 0) ? Wq : (sel == 1) ? Wk : (sel == 2) ? Wv : Wo;
    wt[e] = f2bf(W[k * CC + n]);
}

// ---- shared memory layout (bytes) ----
// XSTRIDE must be a power of 2 >= 224 + swz reach so col^swz stays in-row
// (round-2 bug: stride 240 let ch^swz >= 240 spill into the next row).
#define XSTRIDE  256      // xs/ob row stride (ushorts), swizzled
#define SWZ(row) (((row) & 15) << 3)   // 16 distinct 8-ushort column-block XORs
#define XS_OFF   0        // ushort [64][256]  x staging (later: ob bf16, swizzled) 32768 B
#define QS_OFF   32768    // ushort [64][232]  q (scaled)  29696 B
#define KS_OFF   62464    // ushort [64][232]  k           29696 B
#define VT_OFF   92160    // ushort [224][72]  v transposed: [ch][mcl*16 + widx] 32256 B
#define POS_OFF  124416   // float  [8][16][16]  8192 B
#define ATT_OFF  132608   // ushort [16 waves][16][20]  10240 B
#define SMEM_BYTES 142848
// oout: float [64][225] = 57600 B overlaid on QS..KS (32768 .. 90368 < 92160)

__global__ void __launch_bounds__(1024) attn_fused(
    const float* __restrict__ x, const unsigned short* __restrict__ wt,
    const float* __restrict__ bo, const float* __restrict__ pos,
    const float* __restrict__ scale, float* __restrict__ out)
{
    extern __shared__ char smem[];
    unsigned short* xs   = (unsigned short*)(smem + XS_OFF);
    unsigned short* qs   = (unsigned short*)(smem + QS_OFF);
    unsigned short* ks   = (unsigned short*)(smem + KS_OFF);
    unsigned short* vt   = (unsigned short*)(smem + VT_OFF);
    float*          poss = (float*)         (smem + POS_OFF);
    unsigned short* att  = (unsigned short*)(smem + ATT_OFF);
    unsigned short* ob   = xs;                       // phase2 out / phase3 in (swizzled)
    float*          oout = (float*)(smem + QS_OFF);  // phase3 out (f32 [64][225])

    const int tid = threadIdx.x;
    const int wv  = tid >> 6;        // wave 0..15
    const int l   = tid & 63;
    const int g   = l >> 4;          // 0..3
    const int li  = l & 15;
    const int bid = blockIdx.x;
    const int bi  = bid >> 4;
    const int mr  = (bid >> 1) & 7;
    const int hf  = bid & 1;

    // ---- prologue: stage x -> LDS bf16 [p][ch^swz], stage pos_emb ----
    {
        const float* xb = x + ((size_t)bi * CC << 10);
        for (int q = tid; q < CC * NWIN; q += 1024) {
            int ch = q >> 4, wx = q & 15;
            int wi = wx >> 2, wj = wx & 3;
            int h = wi * 8 + mr, w0 = wj * 8 + hf * 4;
            float4 v4 = *(const float4*)(xb + (ch << 10) + (h << 5) + w0);
            int p = wx * 4;
            xs[(p + 0) * XSTRIDE + (ch ^ SWZ(p + 0))] = f2bf(v4.x);
            xs[(p + 1) * XSTRIDE + (ch ^ SWZ(p + 1))] = f2bf(v4.y);
            xs[(p + 2) * XSTRIDE + (ch ^ SWZ(p + 2))] = f2bf(v4.z);
            xs[(p + 3) * XSTRIDE + (ch ^ SWZ(p + 3))] = f2bf(v4.w);
        }
        for (int e = tid; e < NHEADS * NWIN * NWIN; e += 1024) poss[e] = pos[e];
    }
    const float scl = scale[0];
    __syncthreads();

    // ---- phase 1: Q,K,V = xs @ Wt.  Wave owns M-pair (A in regs), strides N ----
    {
        const int mt2 = wv & 1;
        const int r0 = mt2 * 32 + li, r1 = r0 + 16;
        const int sw = li << 3;                 // SWZ(r0) == SWZ(r1)
        bf16x8 a0[7], a1[7];
        #pragma unroll
        for (int kk = 0; kk < 7; ++kk) {
            int ko = kk * 32 + g * 8;
            a0[kk] = *(const bf16x8*)(xs + r0 * XSTRIDE + (ko ^ sw));
            a1[kk] = *(const bf16x8*)(xs + r1 * XSTRIDE + (ko ^ sw));
        }
        for (int ntg = wv >> 1; ntg < 42; ntg += 8) {
            int sel = ntg / 14, ntl = ntg % 14;
            const unsigned short* wsel = wt + sel * (CC * CC) + (ntl * 16 + li) * CC;
            f32x4 acc0 = {0.f, 0.f, 0.f, 0.f}, acc1 = {0.f, 0.f, 0.f, 0.f};
            #pragma unroll
            for (int kk = 0; kk < 7; ++kk) {
                bf16x8 bf = *(const bf16x8*)(wsel + kk * 32 + g * 8);
                acc0 = __builtin_amdgcn_mfma_f32_16x16x32_bf16(a0[kk], bf, acc0, 0, 0, 0);
                acc1 = __builtin_amdgcn_mfma_f32_16x16x32_bf16(a1[kk], bf, acc1, 0, 0, 0);
            }
            int colb = ntl * 16 + li;
            #pragma unroll
            for (int r = 0; r < 4; ++r) {
                int row0 = mt2 * 32 + g * 4 + r, row1 = row0 + 16;
                float v0 = acc0[r], v1 = acc1[r];
                if (sel == 0) {
                    qs[row0 * 232 + colb] = f2bf(v0 * scl);
                    qs[row1 * 232 + colb] = f2bf(v1 * scl);
                } else if (sel == 1) {
                    ks[row0 * 232 + colb] = f2bf(v0);
                    ks[row1 * 232 + colb] = f2bf(v1);
                } else {
                    vt[colb * 72 + (row0 & 3) * 16 + (row0 >> 2)] = f2bf(v0);
                    vt[colb * 72 + (row1 & 3) * 16 + (row1 >> 2)] = f2bf(v1);
                }
            }
        }
    }
    __syncthreads();

    // ---- phase 2: attention. 2 waves per head, 2 mcl per wave ----
    {
        const int hd = wv >> 1;
        const int cb = hd * DH;
        unsigned short* attw = att + wv * (16 * 20);
        for (int c = 0; c < 2; ++c) {
            int mcl = (wv & 1) * 2 + c;
            int rowq = li * 4 + mcl;
            bf16x8 aq, bk;
            {
                const unsigned short* qp = qs + rowq * 232 + cb + g * 8;
                const unsigned short* kp = ks + rowq * 232 + cb + g * 8;
                u16x4 qlo = *(const u16x4*)qp, qhi = *(const u16x4*)(qp + 4);
                u16x4 klo = *(const u16x4*)kp, khi = *(const u16x4*)(kp + 4);
                if (g == 3) { qhi = (u16x4)0; khi = (u16x4)0; }  // k >= 28 invalid
                for (int j = 0; j < 4; ++j) {
                    aq[j] = (short)qlo[j]; aq[4 + j] = (short)qhi[j];
                    bk[j] = (short)klo[j]; bk[4 + j] = (short)khi[j];
                }
            }
            f32x4 sim = {0.f, 0.f, 0.f, 0.f};
            sim = __builtin_amdgcn_mfma_f32_16x16x32_bf16(aq, bk, sim, 0, 0, 0);
            // softmax: row i = g*4+r across 16 lanes (col j = li)
            #pragma unroll
            for (int r = 0; r < 4; ++r) {
                int i = g * 4 + r;
                float s = sim[r] + poss[(hd * 16 + i) * 16 + li];
                float mx = s;
                mx = fmaxf(mx, __shfl_xor(mx, 1, 16));
                mx = fmaxf(mx, __shfl_xor(mx, 2, 16));
                mx = fmaxf(mx, __shfl_xor(mx, 4, 16));
                mx = fmaxf(mx, __shfl_xor(mx, 8, 16));
                float e = __expf(s - mx);
                float sm = e;
                sm += __shfl_xor(sm, 1, 16);
                sm += __shfl_xor(sm, 2, 16);
                sm += __shfl_xor(sm, 4, 16);
                sm += __shfl_xor(sm, 8, 16);
                attw[i * 20 + li] = f2bf(e / sm);
            }
            // PV: o[i][dh] = sum_j attn[i][j] * v2[j][dh]
            bf16x8 pa;
            if (g < 2) {
                const unsigned short* ap = attw + li * 20 + g * 8;
                u16x4 alo = *(const u16x4*)ap, ahi = *(const u16x4*)(ap + 4);
                for (int j = 0; j < 4; ++j) { pa[j] = (short)alo[j]; pa[4 + j] = (short)ahi[j]; }
            } else {
                pa = (bf16x8)0;
            }
            for (int dt = 0; dt < 2; ++dt) {
                bf16x8 bv;
                if (g < 2) {
                    bv = *(const bf16x8*)(vt + (cb + dt * 16 + li) * 72 + mcl * 16 + g * 8);
                } else {
                    bv = (bf16x8)0;
                }
                f32x4 po = {0.f, 0.f, 0.f, 0.f};
                po = __builtin_amdgcn_mfma_f32_16x16x32_bf16(pa, bv, po, 0, 0, 0);
                int dh = dt * 16 + li;
                if (dh < DH) {
                    #pragma unroll
                    for (int r = 0; r < 4; ++r) {
                        int i = g * 4 + r;
                        int row = i * 4 + mcl;
                        ob[row * XSTRIDE + ((cb + dh) ^ SWZ(row))] = f2bf(po[r]);
                    }
                }
            }
        }
    }
    __syncthreads();

    // ---- phase 3: out = ob @ WoT.  Wave owns M-pair (A in regs), strides N ----
    {
        const int mt2 = wv & 1;
        const int r0 = mt2 * 32 + li, r1 = r0 + 16;
        const int sw = li << 3;                 // SWZ(r0) == SWZ(r1)
        bf16x8 a0[7], a1[7];
        #pragma unroll
        for (int kk = 0; kk < 7; ++kk) {
            int ko = kk * 32 + g * 8;
            a0[kk] = *(const bf16x8*)(ob + r0 * XSTRIDE + (ko ^ sw));
            a1[kk] = *(const bf16x8*)(ob + r1 * XSTRIDE + (ko ^ sw));
        }
        for (int ntl = wv >> 1; ntl < 14; ntl += 8) {
            const unsigned short* wsel = wt + 3 * (CC * CC) + (ntl * 16 + li) * CC;
            f32x4 acc0 = {0.f, 0.f, 0.f, 0.f}, acc1 = {0.f, 0.f, 0.f, 0.f};
            #pragma unroll
            for (int kk = 0; kk < 7; ++kk) {
                bf16x8 bf = *(const bf16x8*)(wsel + kk * 32 + g * 8);
                acc0 = __builtin_amdgcn_mfma_f32_16x16x32_bf16(a0[kk], bf, acc0, 0, 0, 0);
                acc1 = __builtin_amdgcn_mfma_f32_16x16x32_bf16(a1[kk], bf, acc1, 0, 0, 0);
            }
            int colb = ntl * 16 + li;
            #pragma unroll
            for (int r = 0; r < 4; ++r) {
                int row0 = mt2 * 32 + g * 4 + r;
                oout[row0 * 225 + colb] = acc0[r];
                oout[(row0 + 16) * 225 + colb] = acc1[r];
            }
        }
    }
    __syncthreads();

    // ---- final: out[b][ch][h][w] = oout[p][ch] + bo[ch], float4 stores ----
    {
        float* outb = out + ((size_t)bi * CC << 10);
        for (int q = tid; q < CC * NWIN; q += 1024) {
            int ch = q >> 4, wx = q & 15;
            int wi = wx >> 2, wj = wx & 3;
            int h = wi * 8 + mr, w0 = wj * 8 + hf * 4;
            int p = wx * 4;
            float b = bo[ch];
            float4 v4;
            v4.x = oout[(p + 0) * 225 + ch] + b;
            v4.y = oout[(p + 1) * 225 + ch] + b;
            v4.z = oout[(p + 2) * 225 + ch] + b;
            v4.w = oout[(p + 3) * 225 + ch] + b;
            *(float4*)(outb + (ch << 10) + (h << 5) + w0) = v4;
        }
    }
}

extern "C" void kernel_launch(void* const* d_in, const int* in_sizes, int n_in,
                              void* d_out, int out_size, void* d_ws, size_t ws_size,
                              hipStream_t stream) {
    const float* x   = (const float*)d_in[0];
    const float* Wq  = (const float*)d_in[1];
    const float* Wk  = (const float*)d_in[2];
    const float* Wv  = (const float*)d_in[3];
    const float* Wo  = (const float*)d_in[4];
    const float* bo  = (const float*)d_in[5];
    const float* pos = (const float*)d_in[6];
    const float* scl = (const float*)d_in[7];
    float* out = (float*)d_out;
    unsigned short* wt = (unsigned short*)d_ws;   // 4*224*224*2 = 401408 B

    prep_weights<<<dim3((4 * CC * CC + 255) / 256), dim3(256), 0, stream>>>(Wq, Wk, Wv, Wo, wt);

    (void)hipFuncSetAttribute((const void*)attn_fused,
                              hipFuncAttributeMaxDynamicSharedMemorySize, SMEM_BYTES);
    attn_fused<<<dim3(NB * 8 * 2), dim3(1024), SMEM_BYTES, stream>>>(x, wt, bo, pos, scl, out);
}

// Round 4
// 268.163 us; speedup vs baseline: 1.1395x; 1.0075x over previous
//
#include <hip/hip_runtime.h>
#include <stdint.h>

#define NB   128    // batch
#define CC   224    // channels
#define NWIN 16     // windows
#define DH   28     // head dim
#define NHEADS 8

using bf16x8 = __attribute__((ext_vector_type(8))) short;
using u16x4  = __attribute__((ext_vector_type(4))) unsigned short;
using f32x4  = __attribute__((ext_vector_type(4))) float;

__device__ inline unsigned short f2bf(float f) {
    union { float f; unsigned u; } v; v.f = f;
    unsigned u = v.u;
    u += 0x7fffu + ((u >> 16) & 1u);
    return (unsigned short)(u >> 16);
}

// ---- prep: transpose weights to bf16 [sel][n][k], sel = Q,K,V,O ----
__global__ void prep_weights(const float* __restrict__ Wq, const float* __restrict__ Wk,
                             const float* __restrict__ Wv, const float* __restrict__ Wo,
                             unsigned short* __restrict__ wt) {
    int e = blockIdx.x * blockDim.x + threadIdx.x;
    if (e >= 4 * CC * CC) return;
    int sel = e / (CC * CC);
    int rem = e % (CC * CC);
    int n = rem / CC, k = rem % CC;
    const float* W = (sel == 0) ? Wq : (sel == 1) ? Wk : (sel == 2) ? Wv : Wo;
    wt[e] = f2bf(W[k * CC + n]);
}

// ---- shared memory layout (bytes) ----
// XSTRIDE is a power of 2 >= 224 + swz reach so col^swz stays in-row.
#define XSTRIDE  256      // xs/ob row stride (ushorts), swizzled
#define SWZ(row) (((row) & 15) << 3)   // 16 distinct 8-ushort column-block XORs
#define XS_OFF   0        // ushort [64][256]  x staging (later: ob bf16, swizzled) 32768 B
#define QS_OFF   32768    // ushort [64][232]  q (scaled)  29696 B
#define KS_OFF   62464    // ushort [64][232]  k           29696 B
#define VT_OFF   92160    // ushort [224][72]  v transposed: [ch][mcl*16 + widx] 32256 B
#define POS_OFF  124416   // float  [8][16][16]  8192 B
#define ATT_OFF  132608   // ushort [16 waves][16][20]  10240 B
#define SMEM_BYTES 142848
// oout: float [64][225] = 57600 B overlaid on QS..KS (32768 .. 90368 < 92160)

// LDS caps us at 1 block/CU = 16 waves = 4 waves/EU. Tell the register
// allocator: round-3's plain __launch_bounds__(1024) gave VGPR=52 (compiler
// targeted ~9 waves/EU) and rematerialized the A-fragment ds_reads in-loop.
__global__ void __launch_bounds__(1024, 4) attn_fused(
    const float* __restrict__ x, const unsigned short* __restrict__ wt,
    const float* __restrict__ bo, const float* __restrict__ pos,
    const float* __restrict__ scale, float* __restrict__ out)
{
    extern __shared__ char smem[];
    unsigned short* xs   = (unsigned short*)(smem + XS_OFF);
    unsigned short* qs   = (unsigned short*)(smem + QS_OFF);
    unsigned short* ks   = (unsigned short*)(smem + KS_OFF);
    unsigned short* vt   = (unsigned short*)(smem + VT_OFF);
    float*          poss = (float*)         (smem + POS_OFF);
    unsigned short* att  = (unsigned short*)(smem + ATT_OFF);
    unsigned short* ob   = xs;                       // phase2 out / phase3 in (swizzled)
    float*          oout = (float*)(smem + QS_OFF);  // phase3 out (f32 [64][225])

    const int tid = threadIdx.x;
    const int wv  = tid >> 6;        // wave 0..15
    const int l   = tid & 63;
    const int g   = l >> 4;          // 0..3
    const int li  = l & 15;
    const int bid = blockIdx.x;
    const int bi  = bid >> 4;
    const int mr  = (bid >> 1) & 7;
    const int hf  = bid & 1;

    // ---- prologue: stage x -> LDS bf16 [p][ch^swz], stage pos_emb ----
    {
        const float* xb = x + ((size_t)bi * CC << 10);
        for (int q = tid; q < CC * NWIN; q += 1024) {
            int ch = q >> 4, wx = q & 15;
            int wi = wx >> 2, wj = wx & 3;
            int h = wi * 8 + mr, w0 = wj * 8 + hf * 4;
            float4 v4 = *(const float4*)(xb + (ch << 10) + (h << 5) + w0);
            int p = wx * 4;
            xs[(p + 0) * XSTRIDE + (ch ^ SWZ(p + 0))] = f2bf(v4.x);
            xs[(p + 1) * XSTRIDE + (ch ^ SWZ(p + 1))] = f2bf(v4.y);
            xs[(p + 2) * XSTRIDE + (ch ^ SWZ(p + 2))] = f2bf(v4.z);
            xs[(p + 3) * XSTRIDE + (ch ^ SWZ(p + 3))] = f2bf(v4.w);
        }
        for (int e = tid; e < NHEADS * NWIN * NWIN; e += 1024) poss[e] = pos[e];
    }
    const float scl = scale[0];
    __syncthreads();

    // ---- phase 1: Q,K,V = xs @ Wt.  Wave owns M-pair (A pinned in regs), strides N ----
    {
        const int mt2 = wv & 1;
        const int r0 = mt2 * 32 + li, r1 = r0 + 16;
        const int sw = li << 3;                 // SWZ(r0) == SWZ(r1)
        bf16x8 a0[7], a1[7];
        #pragma unroll
        for (int kk = 0; kk < 7; ++kk) {
            int ko = kk * 32 + g * 8;
            a0[kk] = *(const bf16x8*)(xs + r0 * XSTRIDE + (ko ^ sw));
            a1[kk] = *(const bf16x8*)(xs + r1 * XSTRIDE + (ko ^ sw));
        }
        // Pin A-fragments in VGPRs: opaque redefinition blocks rematerializing
        // the ds_reads inside the N-loop.
        #pragma unroll
        for (int kk = 0; kk < 7; ++kk) {
            asm volatile("" : "+v"(a0[kk]), "+v"(a1[kk]));
        }
        for (int ntg = wv >> 1; ntg < 42; ntg += 8) {
            int sel = ntg / 14, ntl = ntg % 14;
            const unsigned short* wsel = wt + sel * (CC * CC) + (ntl * 16 + li) * CC;
            f32x4 acc0 = {0.f, 0.f, 0.f, 0.f}, acc1 = {0.f, 0.f, 0.f, 0.f};
            #pragma unroll
            for (int kk = 0; kk < 7; ++kk) {
                bf16x8 bf = *(const bf16x8*)(wsel + kk * 32 + g * 8);
                acc0 = __builtin_amdgcn_mfma_f32_16x16x32_bf16(a0[kk], bf, acc0, 0, 0, 0);
                acc1 = __builtin_amdgcn_mfma_f32_16x16x32_bf16(a1[kk], bf, acc1, 0, 0, 0);
            }
            int colb = ntl * 16 + li;
            #pragma unroll
            for (int r = 0; r < 4; ++r) {
                int row0 = mt2 * 32 + g * 4 + r, row1 = row0 + 16;
                float v0 = acc0[r], v1 = acc1[r];
                if (sel == 0) {
                    qs[row0 * 232 + colb] = f2bf(v0 * scl);
                    qs[row1 * 232 + colb] = f2bf(v1 * scl);
                } else if (sel == 1) {
                    ks[row0 * 232 + colb] = f2bf(v0);
                    ks[row1 * 232 + colb] = f2bf(v1);
                } else {
                    vt[colb * 72 + (row0 & 3) * 16 + (row0 >> 2)] = f2bf(v0);
                    vt[colb * 72 + (row1 & 3) * 16 + (row1 >> 2)] = f2bf(v1);
                }
            }
        }
    }
    __syncthreads();

    // ---- phase 2: attention. 2 waves per head, 2 mcl per wave ----
    {
        const int hd = wv >> 1;
        const int cb = hd * DH;
        unsigned short* attw = att + wv * (16 * 20);
        for (int c = 0; c < 2; ++c) {
            int mcl = (wv & 1) * 2 + c;
            int rowq = li * 4 + mcl;
            bf16x8 aq, bk;
            {
                const unsigned short* qp = qs + rowq * 232 + cb + g * 8;
                const unsigned short* kp = ks + rowq * 232 + cb + g * 8;
                u16x4 qlo = *(const u16x4*)qp, qhi = *(const u16x4*)(qp + 4);
                u16x4 klo = *(const u16x4*)kp, khi = *(const u16x4*)(kp + 4);
                if (g == 3) { qhi = (u16x4)0; khi = (u16x4)0; }  // k >= 28 invalid
                for (int j = 0; j < 4; ++j) {
                    aq[j] = (short)qlo[j]; aq[4 + j] = (short)qhi[j];
                    bk[j] = (short)klo[j]; bk[4 + j] = (short)khi[j];
                }
            }
            f32x4 sim = {0.f, 0.f, 0.f, 0.f};
            sim = __builtin_amdgcn_mfma_f32_16x16x32_bf16(aq, bk, sim, 0, 0, 0);
            // softmax: row i = g*4+r across 16 lanes (col j = li)
            #pragma unroll
            for (int r = 0; r < 4; ++r) {
                int i = g * 4 + r;
                float s = sim[r] + poss[(hd * 16 + i) * 16 + li];
                float mx = s;
                mx = fmaxf(mx, __shfl_xor(mx, 1, 16));
                mx = fmaxf(mx, __shfl_xor(mx, 2, 16));
                mx = fmaxf(mx, __shfl_xor(mx, 4, 16));
                mx = fmaxf(mx, __shfl_xor(mx, 8, 16));
                float e = __expf(s - mx);
                float sm = e;
                sm += __shfl_xor(sm, 1, 16);
                sm += __shfl_xor(sm, 2, 16);
                sm += __shfl_xor(sm, 4, 16);
                sm += __shfl_xor(sm, 8, 16);
                attw[i * 20 + li] = f2bf(e / sm);
            }
            // PV: o[i][dh] = sum_j attn[i][j] * v2[j][dh]
            bf16x8 pa;
            if (g < 2) {
                const unsigned short* ap = attw + li * 20 + g * 8;
                u16x4 alo = *(const u16x4*)ap, ahi = *(const u16x4*)(ap + 4);
                for (int j = 0; j < 4; ++j) { pa[j] = (short)alo[j]; pa[4 + j] = (short)ahi[j]; }
            } else {
                pa = (bf16x8)0;
            }
            for (int dt = 0; dt < 2; ++dt) {
                bf16x8 bv;
                if (g < 2) {
                    bv = *(const bf16x8*)(vt + (cb + dt * 16 + li) * 72 + mcl * 16 + g * 8);
                } else {
                    bv = (bf16x8)0;
                }
                f32x4 po = {0.f, 0.f, 0.f, 0.f};
                po = __builtin_amdgcn_mfma_f32_16x16x32_bf16(pa, bv, po, 0, 0, 0);
                int dh = dt * 16 + li;
                if (dh < DH) {
                    #pragma unroll
                    for (int r = 0; r < 4; ++r) {
                        int i = g * 4 + r;
                        int row = i * 4 + mcl;
                        ob[row * XSTRIDE + ((cb + dh) ^ SWZ(row))] = f2bf(po[r]);
                    }
                }
            }
        }
    }
    __syncthreads();

    // ---- phase 3: out = ob @ WoT.  Wave owns M-pair (A pinned in regs), strides N ----
    {
        const int mt2 = wv & 1;
        const int r0 = mt2 * 32 + li, r1 = r0 + 16;
        const int sw = li << 3;                 // SWZ(r0) == SWZ(r1)
        bf16x8 a0[7], a1[7];
        #pragma unroll
        for (int kk = 0; kk < 7; ++kk) {
            int ko = kk * 32 + g * 8;
            a0[kk] = *(const bf16x8*)(ob + r0 * XSTRIDE + (ko ^ sw));
            a1[kk] = *(const bf16x8*)(ob + r1 * XSTRIDE + (ko ^ sw));
        }
        #pragma unroll
        for (int kk = 0; kk < 7; ++kk) {
            asm volatile("" : "+v"(a0[kk]), "+v"(a1[kk]));
        }
        for (int ntl = wv >> 1; ntl < 14; ntl += 8) {
            const unsigned short* wsel = wt + 3 * (CC * CC) + (ntl * 16 + li) * CC;
            f32x4 acc0 = {0.f, 0.f, 0.f, 0.f}, acc1 = {0.f, 0.f, 0.f, 0.f};
            #pragma unroll
            for (int kk = 0; kk < 7; ++kk) {
                bf16x8 bf = *(const bf16x8*)(wsel + kk * 32 + g * 8);
                acc0 = __builtin_amdgcn_mfma_f32_16x16x32_bf16(a0[kk], bf, acc0, 0, 0, 0);
                acc1 = __builtin_amdgcn_mfma_f32_16x16x32_bf16(a1[kk], bf, acc1, 0, 0, 0);
            }
            int colb = ntl * 16 + li;
            #pragma unroll
            for (int r = 0; r < 4; ++r) {
                int row0 = mt2 * 32 + g * 4 + r;
                oout[row0 * 225 + colb] = acc0[r];
                oout[(row0 + 16) * 225 + colb] = acc1[r];
            }
        }
    }
    __syncthreads();

    // ---- final: out[b][ch][h][w] = oout[p][ch] + bo[ch], float4 stores ----
    {
        float* outb = out + ((size_t)bi * CC << 10);
        for (int q = tid; q < CC * NWIN; q += 1024) {
            int ch = q >> 4, wx = q & 15;
            int wi = wx >> 2, wj = wx & 3;
            int h = wi * 8 + mr, w0 = wj * 8 + hf * 4;
            int p = wx * 4;
            float b = bo[ch];
            float4 v4;
            v4.x = oout[(p + 0) * 225 + ch] + b;
            v4.y = oout[(p + 1) * 225 + ch] + b;
            v4.z = oout[(p + 2) * 225 + ch] + b;
            v4.w = oout[(p + 3) * 225 + ch] + b;
            *(float4*)(outb + (ch << 10) + (h << 5) + w0) = v4;
        }
    }
}

extern "C" void kernel_launch(void* const* d_in, const int* in_sizes, int n_in,
                              void* d_out, int out_size, void* d_ws, size_t ws_size,
                              hipStream_t stream) {
    const float* x   = (const float*)d_in[0];
    const float* Wq  = (const float*)d_in[1];
    const float* Wk  = (const float*)d_in[2];
    const float* Wv  = (const float*)d_in[3];
    const float* Wo  = (const float*)d_in[4];
    const float* bo  = (const float*)d_in[5];
    const float* pos = (const float*)d_in[6];
    const float* scl = (const float*)d_in[7];
    float* out = (float*)d_out;
    unsigned short* wt = (unsigned short*)d_ws;   // 4*224*224*2 = 401408 B

    prep_weights<<<dim3((4 * CC * CC + 255) / 256), dim3(256), 0, stream>>>(Wq, Wk, Wv, Wo, wt);

    (void)hipFuncSetAttribute((const void*)attn_fused,
                              hipFuncAttributeMaxDynamicSharedMemorySize, SMEM_BYTES);
    attn_fused<<<dim3(NB * 8 * 2), dim3(1024), SMEM_BYTES, stream>>>(x, wt, bo, pos, scl, out);
}

// Round 5
// 244.099 us; speedup vs baseline: 1.2519x; 1.0986x over previous
//
#include <hip/hip_runtime.h>
#include <stdint.h>

#define NB   128    // batch
#define CC   224    // channels
#define NWIN 16     // windows
#define DH   28     // head dim
#define NHEADS 8

using bf16x8 = __attribute__((ext_vector_type(8))) short;
using u16x4  = __attribute__((ext_vector_type(4))) unsigned short;
using f32x4  = __attribute__((ext_vector_type(4))) float;

__device__ inline unsigned short f2bf(float f) {
    union { float f; unsigned u; } v; v.f = f;
    unsigned u = v.u;
    u += 0x7fffu + ((u >> 16) & 1u);
    return (unsigned short)(u >> 16);
}

// ---- prep: transpose weights to bf16 [sel][n][k], sel = Q,K,V,O ----
__global__ void prep_weights(const float* __restrict__ Wq, const float* __restrict__ Wk,
                             const float* __restrict__ Wv, const float* __restrict__ Wo,
                             unsigned short* __restrict__ wt) {
    int e = blockIdx.x * blockDim.x + threadIdx.x;
    if (e >= 4 * CC * CC) return;
    int sel = e / (CC * CC);
    int rem = e % (CC * CC);
    int n = rem / CC, k = rem % CC;
    const float* W = (sel == 0) ? Wq : (sel == 1) ? Wk : (sel == 2) ? Wv : Wo;
    wt[e] = f2bf(W[k * CC + n]);
}

// ---- shared memory layout (bytes), 32-position block ----
// Rows: row = widx + 16*mc2  (widx = window 0..15, mc2 = local col 0..1)
// Overlays (barrier-separated):
//   qs region:  qs (phase1 Q out)  -> ob (phase2 out / phase3 A in)
//   xs region:  xs (x staging)     -> vt (phase1 V out, [ch][row] w=40) -> oout (w/ ks)
//   ks region:  ks (phase1 K out)  -> oout tail
#define QS_OFF   0        // ushort [32][232] = 14848 B
#define XS_OFF   14848    // max(xs [32][232]=14848, vt [224][40]=17920) = 17920 B
#define KS_OFF   32768    // ushort [32][232] = 14848 B
#define ATT_OFF  47616    // ushort [8 waves][16][20] = 5120 B
#define SMEM_BYTES 52736
// oout: float [32][225] = 28800 B at XS_OFF (14848..43647 < 47616)  ✓
// 3 blocks/CU: 3 x 52736 = 158208 <= 163840  ✓

__global__ void __launch_bounds__(512, 6) attn_fused(
    const float* __restrict__ x, const unsigned short* __restrict__ wt,
    const float* __restrict__ bo, const float* __restrict__ pos,
    const float* __restrict__ scale, float* __restrict__ out)
{
    extern __shared__ char smem[];
    unsigned short* qs   = (unsigned short*)(smem + QS_OFF);
    unsigned short* xs   = (unsigned short*)(smem + XS_OFF);
    unsigned short* ks   = (unsigned short*)(smem + KS_OFF);
    unsigned short* att  = (unsigned short*)(smem + ATT_OFF);
    unsigned short* vt   = xs;                       // after B2
    unsigned short* ob   = qs;                       // after B4
    float*          oout = (float*)(smem + XS_OFF);  // after B6

    const int tid = threadIdx.x;
    const int wv  = tid >> 6;        // wave 0..7
    const int l   = tid & 63;
    const int g   = l >> 4;          // 0..3
    const int li  = l & 15;

    // XCD-aware decode: the 4 hq-siblings of each (bi,mr) sit adjacently on
    // one XCD (bid%8 = XCD round-robin) so partial-line writes merge in L2.
    const int bid = blockIdx.x;
    const int xcd = bid & 7;
    const int idx = bid >> 3;        // 0..511 within XCD
    const int hq  = idx & 3;         // column pair {hq*2, hq*2+1}
    const int wg  = (xcd << 7) + (idx >> 2);   // 0..1023
    const int bi  = wg >> 3;
    const int mr  = wg & 7;

    // ---- prologue: stage x -> LDS bf16, rows widx + 16*mc2 ----
    {
        const float* xb = x + ((size_t)bi * CC << 10);
        for (int q = tid; q < CC * NWIN; q += 512) {
            int ch = q >> 4, wx = q & 15;
            int wi = wx >> 2, wj = wx & 3;
            int h = wi * 8 + mr, w0 = wj * 8 + hq * 2;
            float2 v2 = *(const float2*)(xb + (ch << 10) + (h << 5) + w0);
            xs[wx * 232 + ch]        = f2bf(v2.x);   // mc2 = 0
            xs[(wx + 16) * 232 + ch] = f2bf(v2.y);   // mc2 = 1
        }
    }
    const float scl = scale[0];
    __syncthreads();                                  // B1

    // ---- phase 1 A-hoist (xs dead after this) ----
    const int mt = wv & 1;
    const int arow = mt * 16 + li;
    bf16x8 a1f[7];
    #pragma unroll
    for (int kk = 0; kk < 7; ++kk)
        a1f[kk] = *(const bf16x8*)(xs + arow * 232 + kk * 32 + g * 8);
    __syncthreads();                                  // B2 (xs -> vt)

    // ---- phase 1 N-loop: Q,K,V = x @ Wt ----
    for (int ntg = wv >> 1; ntg < 42; ntg += 4) {
        int sel = ntg / 14, ntl = ntg % 14;
        const unsigned short* wsel = wt + sel * (CC * CC) + (ntl * 16 + li) * CC;
        f32x4 acc = {0.f, 0.f, 0.f, 0.f};
        #pragma unroll
        for (int kk = 0; kk < 7; ++kk) {
            bf16x8 bf = *(const bf16x8*)(wsel + kk * 32 + g * 8);
            acc = __builtin_amdgcn_mfma_f32_16x16x32_bf16(a1f[kk], bf, acc, 0, 0, 0);
        }
        int colb = ntl * 16 + li;
        #pragma unroll
        for (int r = 0; r < 4; ++r) {
            int row = mt * 16 + g * 4 + r;
            float v = acc[r];
            if (sel == 0)      qs[row * 232 + colb] = f2bf(v * scl);
            else if (sel == 1) ks[row * 232 + colb] = f2bf(v);
            else               vt[colb * 40 + row]  = f2bf(v);   // [ch][row]
        }
    }
    __syncthreads();                                  // B3

    // ---- phase 2a: QK^T for both mc2 (reads qs/ks), pos prefetch ----
    const int hd = wv;
    const int cb = hd * DH;
    float pv4[4];
    #pragma unroll
    for (int r = 0; r < 4; ++r)
        pv4[r] = pos[(hd * 16 + g * 4 + r) * 16 + li];
    f32x4 sim[2];
    #pragma unroll
    for (int mc2 = 0; mc2 < 2; ++mc2) {
        int rowq = li + mc2 * 16;
        bf16x8 aq, bk;
        const unsigned short* qp = qs + rowq * 232 + cb + g * 8;
        const unsigned short* kp = ks + rowq * 232 + cb + g * 8;
        u16x4 qlo = *(const u16x4*)qp, qhi = *(const u16x4*)(qp + 4);
        u16x4 klo = *(const u16x4*)kp, khi = *(const u16x4*)(kp + 4);
        if (g == 3) { qhi = (u16x4)0; khi = (u16x4)0; }  // k >= 28 invalid
        #pragma unroll
        for (int j = 0; j < 4; ++j) {
            aq[j] = (short)qlo[j]; aq[4 + j] = (short)qhi[j];
            bk[j] = (short)klo[j]; bk[4 + j] = (short)khi[j];
        }
        f32x4 z = {0.f, 0.f, 0.f, 0.f};
        sim[mc2] = __builtin_amdgcn_mfma_f32_16x16x32_bf16(aq, bk, z, 0, 0, 0);
    }
    __syncthreads();                                  // B4 (qs -> ob)

    // ---- phase 2b: softmax + PV, write ob ----
    {
        unsigned short* attw = att + wv * (16 * 20);
        for (int mc2 = 0; mc2 < 2; ++mc2) {
            #pragma unroll
            for (int r = 0; r < 4; ++r) {
                int i = g * 4 + r;
                float s = sim[mc2][r] + pv4[r];
                float mx = s;
                mx = fmaxf(mx, __shfl_xor(mx, 1, 16));
                mx = fmaxf(mx, __shfl_xor(mx, 2, 16));
                mx = fmaxf(mx, __shfl_xor(mx, 4, 16));
                mx = fmaxf(mx, __shfl_xor(mx, 8, 16));
                float e = __expf(s - mx);
                float sm = e;
                sm += __shfl_xor(sm, 1, 16);
                sm += __shfl_xor(sm, 2, 16);
                sm += __shfl_xor(sm, 4, 16);
                sm += __shfl_xor(sm, 8, 16);
                attw[i * 20 + li] = f2bf(e / sm);
            }
            // PV: o[i][dh] = sum_j attn[i][j] * v[j][dh]
            bf16x8 pa;
            if (g < 2) {
                const unsigned short* ap = attw + li * 20 + g * 8;
                u16x4 alo = *(const u16x4*)ap, ahi = *(const u16x4*)(ap + 4);
                #pragma unroll
                for (int j = 0; j < 4; ++j) { pa[j] = (short)alo[j]; pa[4 + j] = (short)ahi[j]; }
            } else {
                pa = (bf16x8)0;
            }
            for (int dt = 0; dt < 2; ++dt) {
                bf16x8 bv;
                if (g < 2) {
                    bv = *(const bf16x8*)(vt + (cb + dt * 16 + li) * 40 + mc2 * 16 + g * 8);
                } else {
                    bv = (bf16x8)0;
                }
                f32x4 po = {0.f, 0.f, 0.f, 0.f};
                po = __builtin_amdgcn_mfma_f32_16x16x32_bf16(pa, bv, po, 0, 0, 0);
                int dh = dt * 16 + li;
                if (dh < DH) {
                    #pragma unroll
                    for (int r = 0; r < 4; ++r) {
                        int i = g * 4 + r;            // window
                        ob[(i + mc2 * 16) * 232 + cb + dh] = f2bf(po[r]);
                    }
                }
            }
        }
    }
    __syncthreads();                                  // B5

    // ---- phase 3 A-hoist from ob ----
    bf16x8 a3f[7];
    #pragma unroll
    for (int kk = 0; kk < 7; ++kk)
        a3f[kk] = *(const bf16x8*)(ob + arow * 232 + kk * 32 + g * 8);
    __syncthreads();                                  // B6 (vt/ks -> oout)

    // ---- phase 3 N-loop: out = o @ WoT ----
    for (int ntl = wv >> 1; ntl < 14; ntl += 4) {
        const unsigned short* wsel = wt + 3 * (CC * CC) + (ntl * 16 + li) * CC;
        f32x4 acc = {0.f, 0.f, 0.f, 0.f};
        #pragma unroll
        for (int kk = 0; kk < 7; ++kk) {
            bf16x8 bf = *(const bf16x8*)(wsel + kk * 32 + g * 8);
            acc = __builtin_amdgcn_mfma_f32_16x16x32_bf16(a3f[kk], bf, acc, 0, 0, 0);
        }
        int colb = ntl * 16 + li;
        #pragma unroll
        for (int r = 0; r < 4; ++r) {
            int row = mt * 16 + g * 4 + r;
            oout[row * 225 + colb] = acc[r];
        }
    }
    __syncthreads();                                  // B7

    // ---- final: out[b][ch][h][w] = oout[row][ch] + bo[ch], float2 stores ----
    {
        float* outb = out + ((size_t)bi * CC << 10);
        for (int q = tid; q < CC * NWIN; q += 512) {
            int ch = q >> 4, wx = q & 15;
            int wi = wx >> 2, wj = wx & 3;
            int h = wi * 8 + mr, w0 = wj * 8 + hq * 2;
            float b = bo[ch];
            float2 v2;
            v2.x = oout[wx * 225 + ch] + b;          // mc2 = 0
            v2.y = oout[(wx + 16) * 225 + ch] + b;   // mc2 = 1
            *(float2*)(outb + (ch << 10) + (h << 5) + w0) = v2;
        }
    }
}

extern "C" void kernel_launch(void* const* d_in, const int* in_sizes, int n_in,
                              void* d_out, int out_size, void* d_ws, size_t ws_size,
                              hipStream_t stream) {
    const float* x   = (const float*)d_in[0];
    const float* Wq  = (const float*)d_in[1];
    const float* Wk  = (const float*)d_in[2];
    const float* Wv  = (const float*)d_in[3];
    const float* Wo  = (const float*)d_in[4];
    const float* bo  = (const float*)d_in[5];
    const float* pos = (const float*)d_in[6];
    const float* scl = (const float*)d_in[7];
    float* out = (float*)d_out;
    unsigned short* wt = (unsigned short*)d_ws;   // 4*224*224*2 = 401408 B

    prep_weights<<<dim3((4 * CC * CC + 255) / 256), dim3(256), 0, stream>>>(Wq, Wk, Wv, Wo, wt);

    (void)hipFuncSetAttribute((const void*)attn_fused,
                              hipFuncAttributeMaxDynamicSharedMemorySize, SMEM_BYTES);
    attn_fused<<<dim3(NB * 8 * 4), dim3(512), SMEM_BYTES, stream>>>(x, wt, bo, pos, scl, out);
}